// Round 1
// baseline (131.432 us; speedup 1.0000x reference)
//
#include <hip/hip_runtime.h>

// ParametricBiquad DF2T, exact wave-level affine scan, fully-coalesced I/O.
//
// R6: two-round waves + cheap uniform-P scan.
//  - Each wave now emits 120 chunks: round 1 = 8 halo + 56 outputs (as R5),
//    round 2 = 64 outputs with entering state CHAINED from round 1's lane-63
//    inclusive scan result (no halo needed).  Read redundancy 1.148x -> 1.067x,
//    waves 9408 -> 4416.
//  - Kogge-Stone simplified: every lane's chunk matrix is the same P = M^32,
//    so at step d the partner's accumulated matrix is wave-uniformly P^d.
//    Scan step = 2 shuffles + 4 FMA (+ shared squaring), vs 6 shuffles + 12 FMA.
//    Halo/tail lanes just contribute f=0 (extra P factors hit the zero base
//    state, harmless); round-2 chain seed is folded into lane 0's element:
//    f0 += P*E, which keeps the uniform-P invariant.
//  - Round-2 x region is prefetched into registers (gv) during round-1 compute,
//    then staged through the same wave-private swizzled LDS (in-order DS ops
//    within a wave make the reuse race-free; validated in R4/R5).

constexpr int B_DIM = 64;
constexpr int L_DIM = 262144;
constexpr int K = 32;                        // samples per lane-chunk (one 128-B line)
constexpr int CPR = L_DIM / K;               // 8192 chunks per row
constexpr int OC1 = 56;                      // round-1 output chunks (lanes 8..63)
constexpr int OC2 = 64;                      // round-2 output chunks (all lanes)
constexpr int OCW = OC1 + OC2;               // 120 outputs per wave
constexpr int WPR = (CPR + OCW - 1) / OCW;   // 69 waves per row
constexpr int TOTAL_WAVES = B_DIM * WPR;     // 4416
constexpr int T = 256;
constexpr int WPB = T / 64;                  // 4 waves per block
constexpr int GRID = TOTAL_WAVES / WPB;      // 1104 blocks
constexpr int RS = 9;                        // LDS row stride in float4 (swizzle)
constexpr int ROWS = 64;                     // 64 chunk-rows per wave region
constexpr int WAVE_LDS = ROWS * RS;          // 576 float4 = 9216 B per wave
constexpr int ROW_F4 = L_DIM / 4;            // 65536 float4 per batch row

#define BIQ_STEP(xs)                                            \
    do {                                                        \
        float yv_ = fmaf(b0, (xs), s1);                         \
        float t1_ = fmaf(b1, (xs), s2);                         \
        s2 = fmaf(-a2, yv_, b2 * (xs));                         \
        s1 = fmaf(-a1, yv_, t1_);                               \
    } while (0)

#define BIQ_STEP_Y(xs, yd)                                      \
    do {                                                        \
        (yd) = fmaf(b0, (xs), s1);                              \
        float t1_ = fmaf(b1, (xs), s2);                         \
        s2 = fmaf(-a2, (yd), b2 * (xs));                        \
        s1 = fmaf(-a1, (yd), t1_);                              \
    } while (0)

// Kogge-Stone inclusive scan of f under uniform chunk matrix P.
// On entry q?? must hold P; clobbers q??.  Updates (f1,f2) in place.
#define CHEAP_SCAN()                                            \
    do {                                                        \
        _Pragma("unroll")                                       \
        for (int d = 1; d < 64; d <<= 1) {                      \
            float g1 = __shfl_up(f1, d, 64);                    \
            float g2 = __shfl_up(f2, d, 64);                    \
            if (lane >= d) {                                    \
                f1 = fmaf(q00, g1, fmaf(q01, g2, f1));          \
                f2 = fmaf(q10, g1, fmaf(q11, g2, f2));          \
            }                                                   \
            float n00 = fmaf(q00, q00, q01 * q10);              \
            float n01 = fmaf(q00, q01, q01 * q11);              \
            float n10 = fmaf(q10, q00, q11 * q10);              \
            float n11 = fmaf(q10, q01, q11 * q11);              \
            q00 = n00; q01 = n01; q10 = n10; q11 = n11;         \
        }                                                       \
    } while (0)

__global__ __launch_bounds__(T, 4) void biquad_wavescan4(
    const float* __restrict__ x,
    const float* __restrict__ coeffs,
    float* __restrict__ y)
{
    __shared__ float4 lds[WPB * WAVE_LDS];   // 4*9216 = 36864 B -> 4 blocks/CU

    const int gtid = blockIdx.x * T + threadIdx.x;
    const int gw   = gtid >> 6;          // global wave id
    const int lane = gtid & 63;
    const int row  = gw / WPR;           // batch row
    const int w    = gw - row * WPR;     // wave index within row

    const int cbase1 = w * OCW - 8;      // round-1 region start chunk (8 halo)
    const int cbase2 = w * OCW + OC1;    // round-2 region start chunk (no halo)
    const int first1 = w * OCW;          // first round-1 output chunk
    int nv1 = CPR - first1; if (nv1 > OC1) nv1 = OC1;   // always >= 1
    int nv2 = CPR - cbase2; if (nv2 > OC2) nv2 = OC2;   // may be <= 0 (last wave)

    float4* wlds = &lds[(threadIdx.x >> 6) * WAVE_LDS];
    const float4* xrow = (const float4*)(x + (size_t)row * L_DIM);
    float4* yrow = (float4*)(y + (size_t)row * L_DIM);

    // ---- stage round-1 region (64 chunks) into LDS, coalesced ----
    const int rbase1 = cbase1 * (K / 4);
    #pragma unroll
    for (int j = 0; j < 8; ++j) {
        int f = j * 64 + lane;                    // 0..511 within region
        int src = rbase1 + f;
        src = src < 0 ? 0 : (src >= ROW_F4 ? ROW_F4 - 1 : src);  // edge waves: garbage-but-safe
        wlds[(f >> 3) * RS + (f & 7)] = xrow[src];
    }

    const float* cf = coeffs + row * 5;
    const float b0 = cf[0], b1 = cf[1], b2 = cf[2];
    const float a1 = cf[3], a2 = cf[4];

    // ---- lane reads own round-1 chunk from LDS into registers ----
    float4 xv[8];
    {
        const float4* rp = &wlds[lane * RS];
        #pragma unroll
        for (int j = 0; j < 8; ++j) xv[j] = rp[j];
    }

    // ---- prefetch round-2 region into registers (hides HBM under round 1) ----
    float4 gv[8];
    const int rbase2 = cbase2 * (K / 4);
    if (nv2 > 0) {
        #pragma unroll
        for (int j = 0; j < 8; ++j) {
            int src = rbase2 + j * 64 + lane;
            src = src >= ROW_F4 ? ROW_F4 - 1 : src;
            gv[j] = xrow[src];
        }
    }

    // ---- P = M^32 via 5 squarings; M = [[-a1,1],[-a2,0]] ----
    float p00 = -a1, p01 = 1.f, p10 = -a2, p11 = 0.f;
    #pragma unroll
    for (int i = 0; i < 5; ++i) {
        float t00 = fmaf(p00, p00, p01 * p10);
        float t01 = fmaf(p00, p01, p01 * p11);
        float t10 = fmaf(p10, p00, p11 * p10);
        float t11 = fmaf(p10, p01, p11 * p11);
        p00 = t00; p01 = t01; p10 = t10; p11 = t11;
    }

    // ================= round 1 =================
    float s1 = 0.f, s2 = 0.f;
    #pragma unroll
    for (int i = 0; i < 8; ++i) {
        BIQ_STEP(xv[i].x); BIQ_STEP(xv[i].y); BIQ_STEP(xv[i].z); BIQ_STEP(xv[i].w);
    }
    const bool act1 = (cbase1 + lane >= 0) && (cbase1 + lane < CPR);
    float f1 = act1 ? s1 : 0.f;
    float f2 = act1 ? s2 : 0.f;

    {
        float q00 = p00, q01 = p01, q10 = p10, q11 = p11;
        CHEAP_SCAN();
    }

    // chain seed for round 2: state entering chunk cbase2 (valid when nv2>0,
    // since then all 64 round-1 lanes are real chunks)
    const float E1 = __shfl(f1, 63, 64);
    const float E2 = __shfl(f2, 63, 64);

    // exclusive: state entering this lane's round-1 chunk
    float e1 = __shfl_up(f1, 1, 64);
    float e2 = __shfl_up(f2, 1, 64);

    if (lane >= 8 && cbase1 + lane < CPR) {
        s1 = e1; s2 = e2;
        float4* wp = &wlds[lane * RS];   // overwrite own x row in place
        #pragma unroll
        for (int i = 0; i < 8; ++i) {
            float4 yv;
            BIQ_STEP_Y(xv[i].x, yv.x);
            BIQ_STEP_Y(xv[i].y, yv.y);
            BIQ_STEP_Y(xv[i].z, yv.z);
            BIQ_STEP_Y(xv[i].w, yv.w);
            wp[i] = yv;
        }
    }

    // coalesced store, round 1 (rows 8..8+nv1)
    {
        float4* ydst = yrow + first1 * (K / 4);
        for (int g = lane; g < nv1 * 8; g += 64) {
            ydst[g] = wlds[((g >> 3) + 8) * RS + (g & 7)];
        }
    }

    // ================= round 2 =================
    if (nv2 > 0) {
        // stage round-2 region from prefetched registers (DS ops are in-order
        // within a wave, so these writes land after the store-loop's reads)
        #pragma unroll
        for (int j = 0; j < 8; ++j) {
            int f = j * 64 + lane;
            wlds[(f >> 3) * RS + (f & 7)] = gv[j];
        }
        {
            const float4* rp = &wlds[lane * RS];
            #pragma unroll
            for (int j = 0; j < 8; ++j) xv[j] = rp[j];
        }

        s1 = 0.f; s2 = 0.f;
        #pragma unroll
        for (int i = 0; i < 8; ++i) {
            BIQ_STEP(xv[i].x); BIQ_STEP(xv[i].y); BIQ_STEP(xv[i].z); BIQ_STEP(xv[i].w);
        }
        const bool act2 = (cbase2 + lane < CPR);
        f1 = act2 ? s1 : 0.f;
        f2 = act2 ? s2 : 0.f;

        // fold chain seed into lane 0's element: chunk0 from state E = P*E + f0
        if (lane == 0) {
            f1 = fmaf(p00, E1, fmaf(p01, E2, f1));
            f2 = fmaf(p10, E1, fmaf(p11, E2, f2));
        }

        {
            float q00 = p00, q01 = p01, q10 = p10, q11 = p11;
            CHEAP_SCAN();
        }

        e1 = __shfl_up(f1, 1, 64);
        e2 = __shfl_up(f2, 1, 64);
        if (lane == 0) { e1 = E1; e2 = E2; }

        if (cbase2 + lane < CPR) {
            s1 = e1; s2 = e2;
            float4* wp = &wlds[lane * RS];
            #pragma unroll
            for (int i = 0; i < 8; ++i) {
                float4 yv;
                BIQ_STEP_Y(xv[i].x, yv.x);
                BIQ_STEP_Y(xv[i].y, yv.y);
                BIQ_STEP_Y(xv[i].z, yv.z);
                BIQ_STEP_Y(xv[i].w, yv.w);
                wp[i] = yv;
            }
        }

        // coalesced store, round 2 (rows 0..nv2)
        float4* ydst = yrow + cbase2 * (K / 4);
        for (int g = lane; g < nv2 * 8; g += 64) {
            ydst[g] = wlds[(g >> 3) * RS + (g & 7)];
        }
    }
}

extern "C" void kernel_launch(void* const* d_in, const int* in_sizes, int n_in,
                              void* d_out, int out_size, void* d_ws, size_t ws_size,
                              hipStream_t stream) {
    const float* x      = (const float*)d_in[0];
    const float* coeffs = (const float*)d_in[1];
    float*       yout   = (float*)d_out;

    biquad_wavescan4<<<GRID, T, 0, stream>>>(x, coeffs, yout);
}

// Round 2
// 114.406 us; speedup vs baseline: 1.1488x; 1.1488x over previous
//
#include <hip/hip_runtime.h>

// ParametricBiquad DF2T, exact wave-level affine scan, fully-coalesced I/O.
//
// R7: revert R6's two-round/register-prefetch experiment (it spilled gv[8] to
// scratch: WRITE 64->98MB, kernel 32->51us) back to the R5 single-round
// structure (9408 waves, latency-hiding wins over redundancy reduction for
// this latency-bound kernel), keeping R6's cheap uniform-P scan.  New:
//  - XOR-swizzled LINEAR LDS (slot(r,c) holds element (r, c^(r&7))): same
//    conflict-free ds_read_b128 pattern as the pad-9 layout but 8192 B/wave
//    -> 32 KiB/block -> 5 blocks/CU (was 4).
//  - global_load_lds width=16 staging with pre-swizzled per-lane global
//    source (linear LDS dest + inverse-swizzled source + swizzled read, the
//    m201 pattern): no VGPR round trip, no ds_write stage, coalescing kept
//    (permutation stays within each 128-B segment).
//  - __launch_bounds__(256,5) so VGPR<=96 fits 5 blocks/CU; no gv -> ~75 regs.
//  - store loop unrolled for the common nv==56 case (batched ds_reads).

constexpr int B_DIM = 64;
constexpr int L_DIM = 262144;
constexpr int K = 32;                        // samples per lane-chunk (one 128-B line)
constexpr int CPR = L_DIM / K;               // 8192 chunks per row
constexpr int OC = 56;                       // output chunks per wave (lanes 8..63)
constexpr int WPR = (CPR + OC - 1) / OC;     // 147 waves per row
constexpr int TOTAL_WAVES = B_DIM * WPR;     // 9408
constexpr int T = 256;
constexpr int WPB = T / 64;                  // 4 waves per block
constexpr int GRID = TOTAL_WAVES / WPB;      // 2352 blocks
constexpr int ROWS = 64;                     // 8 halo + 56 output chunk-rows
constexpr int WAVE_F4 = ROWS * 8;            // 512 float4 = 8192 B per wave
constexpr int ROW_F4 = L_DIM / 4;            // 65536 float4 per batch row

#define BIQ_STEP(xs)                                            \
    do {                                                        \
        float yv_ = fmaf(b0, (xs), s1);                         \
        float t1_ = fmaf(b1, (xs), s2);                         \
        s2 = fmaf(-a2, yv_, b2 * (xs));                         \
        s1 = fmaf(-a1, yv_, t1_);                               \
    } while (0)

#define BIQ_STEP_Y(xs, yd)                                      \
    do {                                                        \
        (yd) = fmaf(b0, (xs), s1);                              \
        float t1_ = fmaf(b1, (xs), s2);                         \
        s2 = fmaf(-a2, (yd), b2 * (xs));                        \
        s1 = fmaf(-a1, (yd), t1_);                              \
    } while (0)

// async global->LDS, 16 B per lane; lds base must be wave-uniform
__device__ __forceinline__ void gld_lds16(const float4* g, float4* l) {
    __builtin_amdgcn_global_load_lds(
        (const __attribute__((address_space(1))) void*)g,
        (__attribute__((address_space(3))) void*)l,
        16, 0, 0);
}

__global__ __launch_bounds__(T, 5) void biquad_wavescan5(
    const float* __restrict__ x,
    const float* __restrict__ coeffs,
    float* __restrict__ y)
{
    __shared__ float4 lds[WPB * WAVE_F4];    // 4*8192 = 32768 B -> 5 blocks/CU

    const int gtid = blockIdx.x * T + threadIdx.x;
    const int gw   = gtid >> 6;          // global wave id
    const int lane = gtid & 63;
    const int row  = gw / WPR;           // batch row
    const int w    = gw - row * WPR;     // wave index within row
    const int c    = w * OC - 8 + lane;  // chunk index; may be <0 or >=CPR

    float4* wlds = &lds[(threadIdx.x >> 6) * WAVE_F4];
    const float4* xrow = (const float4*)(x + (size_t)row * L_DIM);

    // ---- stage wave's 64-chunk region via global_load_lds, coalesced ----
    // LDS slot (r,c) holds element (r, c^(r&7)).  Instruction j writes slots
    // f=j*64+lane linearly; lane therefore fetches global f4
    //   rbase + r*8 + (c^(r&7)),  r=j*8+(lane>>3), c=lane&7  (r&7==lane>>3).
    {
        const int rbase = (w * OC - 8) * 8;           // f4 index of region start
        const int lo3 = lane >> 3, l7 = lane & 7;
        const int csw = l7 ^ lo3;                     // source col within chunk-row
        #pragma unroll
        for (int j = 0; j < 8; ++j) {
            int src = rbase + (j * 8 + lo3) * 8 + csw;
            src = src < 0 ? 0 : (src >= ROW_F4 ? ROW_F4 - 1 : src);  // edge: garbage-but-safe
            gld_lds16(xrow + src, wlds + j * 64);
        }
    }

    const float* cf = coeffs + row * 5;
    const float b0 = cf[0], b1 = cf[1], b2 = cf[2];
    const float a1 = cf[3], a2 = cf[4];

    // ---- lane reads own chunk (row `lane`) from LDS into registers ----
    float4 xv[8];
    {
        const int rb = lane * 8, rx = lane & 7;
        #pragma unroll
        for (int j = 0; j < 8; ++j) xv[j] = wlds[rb + (j ^ rx)];
    }

    // ---- pass 1: run chunk from zero state -> f ----
    float s1 = 0.f, s2 = 0.f;
    #pragma unroll
    for (int i = 0; i < 8; ++i) {
        BIQ_STEP(xv[i].x); BIQ_STEP(xv[i].y); BIQ_STEP(xv[i].z); BIQ_STEP(xv[i].w);
    }

    // ---- P = M^32 via 5 squarings; M = [[-a1,1],[-a2,0]] ----
    float p00 = -a1, p01 = 1.f, p10 = -a2, p11 = 0.f;
    #pragma unroll
    for (int i = 0; i < 5; ++i) {
        float t00 = fmaf(p00, p00, p01 * p10);
        float t01 = fmaf(p00, p01, p01 * p11);
        float t10 = fmaf(p10, p00, p11 * p10);
        float t11 = fmaf(p10, p01, p11 * p11);
        p00 = t00; p01 = t01; p10 = t10; p11 = t11;
    }

    const bool active = (c >= 0) && (c < CPR);
    float f1 = active ? s1 : 0.f;
    float f2 = active ? s2 : 0.f;

    // ---- Kogge-Stone scan of f under uniform chunk matrix P:
    // at step d the partner's accumulated matrix is wave-uniformly P^d, so
    // each step is 2 shuffles + 4 FMA (+ shared squaring).  Inactive lanes
    // contribute f=0; extra P factors hit zero vectors (harmless).
    {
        float q00 = p00, q01 = p01, q10 = p10, q11 = p11;
        #pragma unroll
        for (int d = 1; d < 64; d <<= 1) {
            float g1 = __shfl_up(f1, d, 64);
            float g2 = __shfl_up(f2, d, 64);
            if (lane >= d) {
                f1 = fmaf(q00, g1, fmaf(q01, g2, f1));
                f2 = fmaf(q10, g1, fmaf(q11, g2, f2));
            }
            float n00 = fmaf(q00, q00, q01 * q10);
            float n01 = fmaf(q00, q01, q01 * q11);
            float n10 = fmaf(q10, q00, q11 * q10);
            float n11 = fmaf(q10, q01, q11 * q11);
            q00 = n00; q01 = n01; q10 = n10; q11 = n11;
        }
    }

    // exclusive: state entering this lane's chunk
    float e1 = __shfl_up(f1, 1, 64);
    float e2 = __shfl_up(f2, 1, 64);

    // ---- pass 2: re-run chunk from exact state, write y into own LDS row ----
    if (lane >= 8 && c < CPR) {
        s1 = e1; s2 = e2;
        const int rb = lane * 8, rx = lane & 7;
        #pragma unroll
        for (int i = 0; i < 8; ++i) {
            float4 yv;
            BIQ_STEP_Y(xv[i].x, yv.x);
            BIQ_STEP_Y(xv[i].y, yv.y);
            BIQ_STEP_Y(xv[i].z, yv.z);
            BIQ_STEP_Y(xv[i].w, yv.w);
            wlds[rb + (i ^ rx)] = yv;
        }
    }

    // ---- coalesced global store: consecutive lanes -> consecutive float4 ----
    const int first = w * OC;                          // first output chunk
    int nvalid = CPR - first; if (nvalid > OC) nvalid = OC;
    float4* ydst = (float4*)(y + (size_t)row * L_DIM) + first * 8;
    if (nvalid == OC) {
        #pragma unroll
        for (int it = 0; it < (OC * 8) / 64; ++it) {   // 7 iterations, batched
            int g = it * 64 + lane;
            int r8 = (g >> 3) + 8;
            ydst[g] = wlds[r8 * 8 + ((g & 7) ^ (r8 & 7))];
        }
    } else {
        for (int g = lane; g < nvalid * 8; g += 64) {
            int r8 = (g >> 3) + 8;
            ydst[g] = wlds[r8 * 8 + ((g & 7) ^ (r8 & 7))];
        }
    }
}

extern "C" void kernel_launch(void* const* d_in, const int* in_sizes, int n_in,
                              void* d_out, int out_size, void* d_ws, size_t ws_size,
                              hipStream_t stream) {
    const float* x      = (const float*)d_in[0];
    const float* coeffs = (const float*)d_in[1];
    float*       yout   = (float*)d_out;

    biquad_wavescan5<<<GRID, T, 0, stream>>>(x, coeffs, yout);
}

// Round 5
// 113.348 us; speedup vs baseline: 1.1595x; 1.0093x over previous
//
#include <hip/hip_runtime.h>

// ParametricBiquad DF2T, exact wave-level affine scan, fully-coalesced I/O.
//
// R8 = R7 structure (single round, 9408 waves, XOR-swizzled linear LDS,
// global_load_lds width-16 staging, cheap uniform-P scan) plus:
//  - Correction-form pass 2: pass 1 computes the forced response y0 (zero
//    entering state) IN PLACE in xv registers; true output is
//    y_n = y0_n + (M^n e)_1, so pass 2 is a pure-decay iteration v <- M v
//    (1 dependent FMA/step vs the 2-FMA biquad chain; 3 VALU ops/sample vs 4).
//    Halves the post-scan serial chain (~256 -> ~128 cyc/wave).
//  - XCD-aware bijective block swizzle (GRID=2352 % 8 == 0): consecutive
//    waves of a row share 8-chunk halos; putting them on the same XCD turns
//    halo re-reads into L2 hits.
// (R3/R4 submissions were identical; both benches failed on container
//  acquisition — audited the kernel for hang/OOB causes, found none.
//  This is a clean re-run, not a new experiment.)

constexpr int B_DIM = 64;
constexpr int L_DIM = 262144;
constexpr int K = 32;                        // samples per lane-chunk (one 128-B line)
constexpr int CPR = L_DIM / K;               // 8192 chunks per row
constexpr int OC = 56;                       // output chunks per wave (lanes 8..63)
constexpr int WPR = (CPR + OC - 1) / OC;     // 147 waves per row
constexpr int TOTAL_WAVES = B_DIM * WPR;     // 9408
constexpr int T = 256;
constexpr int WPB = T / 64;                  // 4 waves per block
constexpr int GRID = TOTAL_WAVES / WPB;      // 2352 blocks
constexpr int NXCD = 8;
constexpr int CPX = GRID / NXCD;             // 294 (exact: 2352 % 8 == 0)
constexpr int ROWS = 64;                     // 8 halo + 56 output chunk-rows
constexpr int WAVE_F4 = ROWS * 8;            // 512 float4 = 8192 B per wave
constexpr int ROW_F4 = L_DIM / 4;            // 65536 float4 per batch row

// forced-response step, in place: v holds x on entry, y0 on exit
#define BIQ_STEP_IP(v)                                          \
    do {                                                        \
        float xs_ = (v);                                        \
        (v) = fmaf(b0, xs_, s1);                                \
        float t1_ = fmaf(b1, xs_, s2);                          \
        s2 = fmaf(-a2, (v), b2 * xs_);                          \
        s1 = fmaf(-a1, (v), t1_);                               \
    } while (0)

// homogeneous correction: y = y0 + v1, then v <- M v  (M = [[-a1,1],[-a2,0]])
#define BIQ_CORR(v)                                             \
    do {                                                        \
        (v) += v1;                                              \
        float nv_ = fmaf(-a1, v1, v2);                          \
        v2 = -a2 * v1;                                          \
        v1 = nv_;                                               \
    } while (0)

// async global->LDS, 16 B per lane; lds base must be wave-uniform
__device__ __forceinline__ void gld_lds16(const float4* g, float4* l) {
    __builtin_amdgcn_global_load_lds(
        (const __attribute__((address_space(1))) void*)g,
        (__attribute__((address_space(3))) void*)l,
        16, 0, 0);
}

__global__ __launch_bounds__(T, 5) void biquad_wavescan6(
    const float* __restrict__ x,
    const float* __restrict__ coeffs,
    float* __restrict__ y)
{
    __shared__ float4 lds[WPB * WAVE_F4];    // 4*8192 = 32768 B -> 5 blocks/CU

    // XCD-aware bijective swizzle: blocks on one XCD get contiguous work,
    // so neighbor waves' 8-chunk halo overlap hits the same L2.
    const int bid  = blockIdx.x;
    const int sbid = (bid % NXCD) * CPX + bid / NXCD;

    const int gtid = sbid * T + threadIdx.x;
    const int gw   = gtid >> 6;          // global wave id
    const int lane = gtid & 63;
    const int row  = gw / WPR;           // batch row
    const int w    = gw - row * WPR;     // wave index within row
    const int c    = w * OC - 8 + lane;  // chunk index; may be <0 or >=CPR

    float4* wlds = &lds[(threadIdx.x >> 6) * WAVE_F4];
    const float4* xrow = (const float4*)(x + (size_t)row * L_DIM);

    // ---- stage wave's 64-chunk region via global_load_lds, coalesced ----
    // LDS slot (r,c) holds element (r, c^(r&7)).  Instruction j writes slots
    // f=j*64+lane linearly; lane therefore fetches global f4
    //   rbase + r*8 + (c^(r&7)),  r=j*8+(lane>>3), c=lane&7  (r&7==lane>>3).
    {
        const int rbase = (w * OC - 8) * 8;           // f4 index of region start
        const int lo3 = lane >> 3, l7 = lane & 7;
        const int csw = l7 ^ lo3;                     // source col within chunk-row
        #pragma unroll
        for (int j = 0; j < 8; ++j) {
            int src = rbase + (j * 8 + lo3) * 8 + csw;
            src = src < 0 ? 0 : (src >= ROW_F4 ? ROW_F4 - 1 : src);  // edge: garbage-but-safe
            gld_lds16(xrow + src, wlds + j * 64);
        }
    }

    const float* cf = coeffs + row * 5;
    const float b0 = cf[0], b1 = cf[1], b2 = cf[2];
    const float a1 = cf[3], a2 = cf[4];

    // ---- lane reads own chunk (row `lane`) from LDS into registers ----
    float4 xv[8];
    {
        const int rb = lane * 8, rx = lane & 7;
        #pragma unroll
        for (int j = 0; j < 8; ++j) xv[j] = wlds[rb + (j ^ rx)];
    }

    // ---- pass 1: forced response from zero state; y0 replaces x in xv ----
    float s1 = 0.f, s2 = 0.f;
    #pragma unroll
    for (int i = 0; i < 8; ++i) {
        BIQ_STEP_IP(xv[i].x); BIQ_STEP_IP(xv[i].y);
        BIQ_STEP_IP(xv[i].z); BIQ_STEP_IP(xv[i].w);
    }

    // ---- P = M^32 via 5 squarings; M = [[-a1,1],[-a2,0]] ----
    float p00 = -a1, p01 = 1.f, p10 = -a2, p11 = 0.f;
    #pragma unroll
    for (int i = 0; i < 5; ++i) {
        float t00 = fmaf(p00, p00, p01 * p10);
        float t01 = fmaf(p00, p01, p01 * p11);
        float t10 = fmaf(p10, p00, p11 * p10);
        float t11 = fmaf(p10, p01, p11 * p11);
        p00 = t00; p01 = t01; p10 = t10; p11 = t11;
    }

    const bool active = (c >= 0) && (c < CPR);
    float f1 = active ? s1 : 0.f;
    float f2 = active ? s2 : 0.f;

    // ---- Kogge-Stone scan of f under uniform chunk matrix P:
    // at step d the partner's accumulated matrix is wave-uniformly P^d, so
    // each step is 2 shuffles + 4 FMA (+ shared squaring).  Inactive lanes
    // contribute f=0; extra P factors hit zero vectors (harmless).
    {
        float q00 = p00, q01 = p01, q10 = p10, q11 = p11;
        #pragma unroll
        for (int d = 1; d < 64; d <<= 1) {
            float g1 = __shfl_up(f1, d, 64);
            float g2 = __shfl_up(f2, d, 64);
            if (lane >= d) {
                f1 = fmaf(q00, g1, fmaf(q01, g2, f1));
                f2 = fmaf(q10, g1, fmaf(q11, g2, f2));
            }
            float n00 = fmaf(q00, q00, q01 * q10);
            float n01 = fmaf(q00, q01, q01 * q11);
            float n10 = fmaf(q10, q00, q11 * q10);
            float n11 = fmaf(q10, q01, q11 * q11);
            q00 = n00; q01 = n01; q10 = n10; q11 = n11;
        }
    }

    // exclusive: state entering this lane's chunk
    float e1 = __shfl_up(f1, 1, 64);
    float e2 = __shfl_up(f2, 1, 64);

    // ---- pass 2: homogeneous correction y = y0 + (M^n e)_1, write to LDS ----
    if (lane >= 8 && c < CPR) {
        float v1 = e1, v2 = e2;
        const int rb = lane * 8, rx = lane & 7;
        #pragma unroll
        for (int i = 0; i < 8; ++i) {
            BIQ_CORR(xv[i].x); BIQ_CORR(xv[i].y);
            BIQ_CORR(xv[i].z); BIQ_CORR(xv[i].w);
            wlds[rb + (i ^ rx)] = xv[i];
        }
    }

    // ---- coalesced global store: consecutive lanes -> consecutive float4 ----
    const int first = w * OC;                          // first output chunk
    int nvalid = CPR - first; if (nvalid > OC) nvalid = OC;
    float4* ydst = (float4*)(y + (size_t)row * L_DIM) + first * 8;
    if (nvalid == OC) {
        #pragma unroll
        for (int it = 0; it < (OC * 8) / 64; ++it) {   // 7 iterations, batched
            int g = it * 64 + lane;
            int r8 = (g >> 3) + 8;
            ydst[g] = wlds[r8 * 8 + ((g & 7) ^ (r8 & 7))];
        }
    } else {
        for (int g = lane; g < nvalid * 8; g += 64) {
            int r8 = (g >> 3) + 8;
            ydst[g] = wlds[r8 * 8 + ((g & 7) ^ (r8 & 7))];
        }
    }
}

extern "C" void kernel_launch(void* const* d_in, const int* in_sizes, int n_in,
                              void* d_out, int out_size, void* d_ws, size_t ws_size,
                              hipStream_t stream) {
    const float* x      = (const float*)d_in[0];
    const float* coeffs = (const float*)d_in[1];
    float*       yout   = (float*)d_out;

    biquad_wavescan6<<<GRID, T, 0, stream>>>(x, coeffs, yout);
}